// Round 1
// baseline (657.344 us; speedup 1.0000x reference)
//
#include <hip/hip_runtime.h>
#include <hip/hip_bf16.h>

// Problem constants (from reference)
#define N0C   200000
#define N1C   50000
#define N2C   10000
#define INF   602
#define KP    608      // K padded to 19*32 for 16x16x32 MFMA
#define HID   128
#define CLS   41
#define FAN   25

typedef __attribute__((ext_vector_type(8))) short short8;
typedef __attribute__((ext_vector_type(4))) float float4v;

__device__ __forceinline__ unsigned short f2bf(float f) {
    union { float f; unsigned u; } v; v.f = f;
    unsigned u = v.u;
    unsigned r = u + 0x7fffu + ((u >> 16) & 1u);   // round-to-nearest-even
    return (unsigned short)(r >> 16);
}

// Kernel 0: W1 fp32 [128 x 602] -> bf16 [128 x 608] zero-padded, row-major
__global__ void prep_w1(const float* __restrict__ W1, unsigned short* __restrict__ W1b) {
    int i = blockIdx.x * blockDim.x + threadIdx.x;
    if (i >= HID * KP) return;
    int h = i / KP, k = i - h * KP;
    float v = (k < INF) ? W1[h * INF + k] : 0.0f;
    W1b[i] = f2bf(v);
}

// Kernel 1: h1[i,:] = relu(features[map1[i],:] @ W1^T + b1), i < N1
// LDS-free MFMA GEMM. One wave computes a 16(M) x 128(N) tile.
// Block = 256 threads = 4 waves = 64 rows. Grid = ceil(N1/64).
__launch_bounds__(256)
__global__ void gemm1(const float* __restrict__ feat,
                      const unsigned short* __restrict__ W1b,
                      const float* __restrict__ b1,
                      const int* __restrict__ map1,
                      float* __restrict__ h1) {
    const int wave = threadIdx.x >> 6;
    const int lane = threadIdx.x & 63;
    const int quad = lane >> 4;
    const int l16  = lane & 15;
    const int mbase = blockIdx.x * 64 + wave * 16;

    // A operand: lane holds A[m = l16][k = quad*8 + j], j=0..7
    int arow = mbase + l16;
    if (arow >= N1C) arow = 0;                       // safe dummy row
    const float* aptr = feat + (long)map1[arow] * INF + quad * 8;

    // B operand: lane holds B[k = quad*8+j][n = nt*16 + l16] = W1[n][k]
    const unsigned short* bbase = W1b + (long)l16 * KP + quad * 8;

    float4v acc[8];
    #pragma unroll
    for (int i = 0; i < 8; ++i) acc[i] = (float4v){0.f, 0.f, 0.f, 0.f};

    for (int kt = 0; kt < KP / 32; ++kt) {
        const int k0 = kt * 32;
        float af[8];
        if (k0 + 32 <= INF) {
            // fast path: 4x float2 (rows are 8B-aligned: 602*4 = 2408 B stride)
            const float2* p = (const float2*)(aptr + k0);
            float2 x0 = p[0], x1 = p[1], x2 = p[2], x3 = p[3];
            af[0] = x0.x; af[1] = x0.y; af[2] = x1.x; af[3] = x1.y;
            af[4] = x2.x; af[5] = x2.y; af[6] = x3.x; af[7] = x3.y;
        } else {
            // K tail (last iteration only): guarded scalar loads, pad with 0
            #pragma unroll
            for (int j = 0; j < 8; ++j) {
                int k = k0 + quad * 8 + j;
                af[j] = (k < INF) ? aptr[k0 + j] : 0.0f;
            }
        }
        short8 a;
        #pragma unroll
        for (int j = 0; j < 8; ++j) a[j] = (short)f2bf(af[j]);

        #pragma unroll
        for (int nt = 0; nt < 8; ++nt) {
            const short8 b = *(const short8*)(bbase + (long)nt * 16 * KP + k0);
            acc[nt] = __builtin_amdgcn_mfma_f32_16x16x32_bf16(a, b, acc[nt], 0, 0, 0);
        }
    }

    // Epilogue. C/D layout: col = l16 (N), row = quad*4 + reg (M).
    #pragma unroll
    for (int nt = 0; nt < 8; ++nt) {
        const int col = nt * 16 + l16;
        const float bias = b1[col];
        #pragma unroll
        for (int r = 0; r < 4; ++r) {
            const int row = mbase + quad * 4 + r;
            if (row < N1C) {
                float v = acc[nt][r] + bias;
                h1[(long)row * HID + col] = v > 0.f ? v : 0.f;
            }
        }
    }
}

// Kernel 2: per seed node n: agg = mean_{j<25} h1[nidx[n,j],:]; out = agg @ W2^T + b2
// One block (128 threads) per seed node.
__launch_bounds__(128)
__global__ void agg_out(const float* __restrict__ h1,
                        const int* __restrict__ nidx,
                        const float* __restrict__ W2,
                        const float* __restrict__ b2,
                        float* __restrict__ out) {
    __shared__ float agg[HID];
    __shared__ int idx[FAN];
    const int n = blockIdx.x;
    const int t = threadIdx.x;
    if (t < FAN) idx[t] = nidx[n * FAN + t];
    __syncthreads();
    float s = 0.f;
    #pragma unroll 5
    for (int j = 0; j < FAN; ++j) s += h1[(long)idx[j] * HID + t];
    agg[t] = s * (1.0f / FAN);
    __syncthreads();
    if (t < CLS) {
        float o = b2[t];
        const float* w = W2 + t * HID;
        #pragma unroll 8
        for (int h = 0; h < HID; ++h) o += agg[h] * w[h];
        out[n * CLS + t] = o;
    }
}

extern "C" void kernel_launch(void* const* d_in, const int* in_sizes, int n_in,
                              void* d_out, int out_size, void* d_ws, size_t ws_size,
                              hipStream_t stream) {
    const float* feat = (const float*)d_in[0];
    const float* W1   = (const float*)d_in[1];
    const float* b1   = (const float*)d_in[2];
    const float* W2   = (const float*)d_in[3];
    const float* b2   = (const float*)d_in[4];
    const int*   map1 = (const int*)d_in[5];
    const int*   nix  = (const int*)d_in[6];
    float* out = (float*)d_out;

    // workspace layout: [W1 bf16 padded | h1 fp32]
    unsigned short* W1b = (unsigned short*)d_ws;
    size_t off = ((size_t)HID * KP * sizeof(unsigned short) + 255) & ~(size_t)255;
    float* h1 = (float*)((char*)d_ws + off);

    prep_w1<<<(HID * KP + 255) / 256, 256, 0, stream>>>(W1, W1b);
    gemm1<<<(N1C + 63) / 64, 256, 0, stream>>>(feat, W1b, b1, map1, h1);
    agg_out<<<N2C, 128, 0, stream>>>(h1, nix, W2, b2, out);
}

// Round 2
// 644.134 us; speedup vs baseline: 1.0205x; 1.0205x over previous
//
#include <hip/hip_runtime.h>
#include <hip/hip_bf16.h>

// Problem constants (from reference)
#define N0C   200000
#define N1C   50000
#define N2C   10000
#define INF   602
#define KP    608      // K padded to 19*32 for 16x16x32 MFMA
#define HID   128
#define CLS   41
#define FAN   25

typedef __attribute__((ext_vector_type(8))) short short8;
typedef __attribute__((ext_vector_type(4))) float float4v;

__device__ __forceinline__ unsigned short f2bf(float f) {
    union { float f; unsigned u; } v; v.f = f;
    unsigned u = v.u;
    unsigned r = u + 0x7fffu + ((u >> 16) & 1u);   // round-to-nearest-even
    return (unsigned short)(r >> 16);
}

__device__ __forceinline__ float bf2f(unsigned short b) {
    union { unsigned u; float f; } v; v.u = ((unsigned)b) << 16;
    return v.f;
}

// Kernel 0: W1 fp32 [128 x 602] -> bf16 [128 x 608] zero-padded, row-major
__global__ void prep_w1(const float* __restrict__ W1, unsigned short* __restrict__ W1b) {
    int i = blockIdx.x * blockDim.x + threadIdx.x;
    if (i >= HID * KP) return;
    int h = i / KP, k = i - h * KP;
    float v = (k < INF) ? W1[h * INF + k] : 0.0f;
    W1b[i] = f2bf(v);
}

// Kernel 1: h1[i,:] = relu(features[map1[i],:] @ W1^T + b1), i < N1, stored bf16.
// LDS-free MFMA GEMM. One wave computes a 16(M) x 128(N) tile.
// Block = 256 threads = 4 waves = 64 rows. Grid = ceil(N1/64).
__launch_bounds__(256)
__global__ void gemm1(const float* __restrict__ feat,
                      const unsigned short* __restrict__ W1b,
                      const float* __restrict__ b1,
                      const int* __restrict__ map1,
                      unsigned short* __restrict__ h1b) {
    const int wave = threadIdx.x >> 6;
    const int lane = threadIdx.x & 63;
    const int quad = lane >> 4;
    const int l16  = lane & 15;
    const int mbase = blockIdx.x * 64 + wave * 16;

    // A operand: lane holds A[m = l16][k = quad*8 + j], j=0..7
    int arow = mbase + l16;
    if (arow >= N1C) arow = 0;                       // safe dummy row
    const float* aptr = feat + (long)map1[arow] * INF + quad * 8;

    // B operand: lane holds B[k = quad*8+j][n = nt*16 + l16] = W1[n][k]
    const unsigned short* bbase = W1b + (long)l16 * KP + quad * 8;

    float4v acc[8];
    #pragma unroll
    for (int i = 0; i < 8; ++i) acc[i] = (float4v){0.f, 0.f, 0.f, 0.f};

    for (int kt = 0; kt < KP / 32; ++kt) {
        const int k0 = kt * 32;
        float af[8];
        if (k0 + 32 <= INF) {
            // fast path: 4x float2 (rows are 8B-aligned: 602*4 = 2408 B stride)
            const float2* p = (const float2*)(aptr + k0);
            float2 x0 = p[0], x1 = p[1], x2 = p[2], x3 = p[3];
            af[0] = x0.x; af[1] = x0.y; af[2] = x1.x; af[3] = x1.y;
            af[4] = x2.x; af[5] = x2.y; af[6] = x3.x; af[7] = x3.y;
        } else {
            // K tail (last iteration only): guarded scalar loads, pad with 0
            #pragma unroll
            for (int j = 0; j < 8; ++j) {
                int k = k0 + quad * 8 + j;
                af[j] = (k < INF) ? aptr[k0 + j] : 0.0f;
            }
        }
        short8 a;
        #pragma unroll
        for (int j = 0; j < 8; ++j) a[j] = (short)f2bf(af[j]);

        #pragma unroll
        for (int nt = 0; nt < 8; ++nt) {
            const short8 b = *(const short8*)(bbase + (long)nt * 16 * KP + k0);
            acc[nt] = __builtin_amdgcn_mfma_f32_16x16x32_bf16(a, b, acc[nt], 0, 0, 0);
        }
    }

    // Epilogue. C/D layout: col = l16 (N), row = quad*4 + reg (M). Store bf16.
    #pragma unroll
    for (int nt = 0; nt < 8; ++nt) {
        const int col = nt * 16 + l16;
        const float bias = b1[col];
        #pragma unroll
        for (int r = 0; r < 4; ++r) {
            const int row = mbase + quad * 4 + r;
            if (row < N1C) {
                float v = acc[nt][r] + bias;
                h1b[(long)row * HID + col] = f2bf(v > 0.f ? v : 0.f);
            }
        }
    }
}

// Kernel 2: one WAVE per seed node. Lane reads one uint (2 bf16 cols) per
// neighbor row -> 64 lanes x 4 B = fully coalesced 256 B per row read.
// Block = 256 threads = 4 waves = 4 seeds. Grid = N2/4 (exact: 10000 = 2500*4).
__launch_bounds__(256)
__global__ void agg_out(const unsigned int* __restrict__ h1w,   // h1 as uint (2 bf16)
                        const int* __restrict__ nidx,
                        const float* __restrict__ W2,
                        const float* __restrict__ b2,
                        float* __restrict__ out) {
    __shared__ float agg[4][HID];
    const int wave = threadIdx.x >> 6;
    const int lane = threadIdx.x & 63;
    const int n = blockIdx.x * 4 + wave;

    // each lane j<FAN loads one neighbor index; broadcast via shfl
    int myidx = (lane < FAN) ? nidx[n * FAN + lane] : 0;

    float s0 = 0.f, s1 = 0.f;
    #pragma unroll
    for (int j = 0; j < FAN; ++j) {
        int row = __shfl(myidx, j);
        unsigned int w = h1w[(long)row * 64 + lane];   // cols 2*lane, 2*lane+1
        s0 += bf2f((unsigned short)(w & 0xffffu));
        s1 += bf2f((unsigned short)(w >> 16));
    }
    agg[wave][2 * lane]     = s0 * (1.0f / FAN);
    agg[wave][2 * lane + 1] = s1 * (1.0f / FAN);
    __syncthreads();

    if (lane < CLS) {
        float o = b2[lane];
        const float* w = W2 + lane * HID;
        const float* a = agg[wave];
        #pragma unroll 8
        for (int h = 0; h < HID; ++h) o += a[h] * w[h];
        out[n * CLS + lane] = o;
    }
}

extern "C" void kernel_launch(void* const* d_in, const int* in_sizes, int n_in,
                              void* d_out, int out_size, void* d_ws, size_t ws_size,
                              hipStream_t stream) {
    const float* feat = (const float*)d_in[0];
    const float* W1   = (const float*)d_in[1];
    const float* b1   = (const float*)d_in[2];
    const float* W2   = (const float*)d_in[3];
    const float* b2   = (const float*)d_in[4];
    const int*   map1 = (const int*)d_in[5];
    const int*   nix  = (const int*)d_in[6];
    float* out = (float*)d_out;

    // workspace layout: [W1 bf16 padded | h1 bf16]
    unsigned short* W1b = (unsigned short*)d_ws;
    size_t off = ((size_t)HID * KP * sizeof(unsigned short) + 255) & ~(size_t)255;
    unsigned short* h1b = (unsigned short*)((char*)d_ws + off);

    prep_w1<<<(HID * KP + 255) / 256, 256, 0, stream>>>(W1, W1b);
    gemm1<<<(N1C + 63) / 64, 256, 0, stream>>>(feat, W1b, b1, map1, h1b);
    agg_out<<<N2C / 4, 256, 0, stream>>>((const unsigned int*)h1b, nix, W2, b2, out);
}